// Round 1
// baseline (60.662 us; speedup 1.0000x reference)
//
#include <hip/hip_runtime.h>

// N3Tree vertical query: per-point octree descent (N=2, DEPTH=6, DATA_DIM=4).
// One thread per query point. Tree arrays (~3 MB) are L2-resident; streaming
// traffic is indices (48 MB read) + output (64 MB write) -> memory-bound.
__global__ __launch_bounds__(256) void n3tree_query_kernel(
    const float* __restrict__ data,      // (total, 2,2,2, 4) f32
    const int*   __restrict__ child,     // (total, 2,2,2)    i32
    const float* __restrict__ indices,   // (Q, 3)            f32
    const float* __restrict__ offset,    // (3,)              f32
    const float* __restrict__ invradius, // (1,)              f32
    float*       __restrict__ out,       // (Q, 4)            f32
    int q)
{
    int i = blockIdx.x * blockDim.x + threadIdx.x;
    if (i >= q) return;

    const float inv = invradius[0];
    const float ox = offset[0], oy = offset[1], oz = offset[2];

    // offset + indices * invradius, clipped to [0, 1-1e-10] (== [0,1] in fp32)
    const float HI = 1.0f - 1e-10f;  // rounds to 1.0f, same as the reference's fp32 bound
    float x = fminf(fmaxf(indices[3 * i + 0] * inv + ox, 0.0f), HI);
    float y = fminf(fmaxf(indices[3 * i + 1] * inv + oy, 0.0f), HI);
    float z = fminf(fmaxf(indices[3 * i + 2] * inv + oz, 0.0f), HI);

    int node = 0;
    float4 res = make_float4(0.f, 0.f, 0.f, 0.f);

#pragma unroll
    for (int l = 0; l < 6; ++l) {
        x *= 2.0f; y *= 2.0f; z *= 2.0f;
        float fx = fminf(floorf(x), 1.0f);
        float fy = fminf(floorf(y), 1.0f);
        float fz = fminf(floorf(z), 1.0f);
        x -= fx; y -= fy; z -= fz;
        int cell = (((int)fx) << 2) | (((int)fy) << 1) | ((int)fz);
        int idx = (node << 3) + cell;          // node*8 + cell
        int delta = child[idx];
        if (delta == 0) {
            // leaf: gather the 4 contiguous floats (16B-aligned)
            res = *reinterpret_cast<const float4*>(data + (size_t)idx * 4);
            break;
        }
        node += delta;
    }

    *reinterpret_cast<float4*>(out + (size_t)i * 4) = res;
}

extern "C" void kernel_launch(void* const* d_in, const int* in_sizes, int n_in,
                              void* d_out, int out_size, void* d_ws, size_t ws_size,
                              hipStream_t stream) {
    const float* data      = (const float*)d_in[0];
    const int*   child     = (const int*)d_in[1];
    const float* indices   = (const float*)d_in[2];
    const float* offset    = (const float*)d_in[3];
    const float* invradius = (const float*)d_in[4];
    float* out = (float*)d_out;

    int q = in_sizes[2] / 3;  // indices is (Q,3)
    int block = 256;
    int grid = (q + block - 1) / block;
    n3tree_query_kernel<<<grid, block, 0, stream>>>(
        data, child, indices, offset, invradius, out, q);
}